// Round 9
// baseline (349.033 us; speedup 1.0000x reference)
//
#include <hip/hip_runtime.h>
#include <hip/hip_bf16.h>
#include <type_traits>

typedef unsigned short u16;
typedef __attribute__((ext_vector_type(4))) float f32x4;
typedef __attribute__((ext_vector_type(8))) short short8;
typedef __attribute__((ext_vector_type(4))) short short4v;
typedef __attribute__((ext_vector_type(8))) __bf16 bf16x8;
typedef __attribute__((ext_vector_type(4))) __bf16 bf16x4;

#define BB 2
#define NN 2048
#define DDIM 1024
#define HH 8
#define QHH 16
#define DHH 64

__device__ __forceinline__ float b2f(u16 v) {
    return __builtin_bit_cast(float, ((unsigned)v) << 16);
}
__device__ __forceinline__ u16 f2b(float f) {
    unsigned u = __builtin_bit_cast(unsigned, f);
    u += 0x7FFFu + ((u >> 16) & 1u);   // RNE
    return (u16)(u >> 16);
}
__device__ __forceinline__ float fastrcp(float x) {
#if __has_builtin(__builtin_amdgcn_rcpf)
    return __builtin_amdgcn_rcpf(x);
#else
    return 1.0f / x;
#endif
}
__device__ __forceinline__ float fastexp2(float x) {
#if __has_builtin(__builtin_amdgcn_exp2f)
    return __builtin_amdgcn_exp2f(x);  // v_exp_f32; NB: __exp2f collides with glibc
#else
    return exp2f(x);
#endif
}
__device__ __forceinline__ f32x4 mfma16(short8 a, short8 b, f32x4 c) {
    return __builtin_amdgcn_mfma_f32_16x16x32_bf16(
        __builtin_bit_cast(bf16x8, a), __builtin_bit_cast(bf16x8, b), c, 0, 0, 0);
}
// K=16 MFMA for register-direct P^T (B-operand = C-layout of S^T — no LDS round-trip)
#if __has_builtin(__builtin_amdgcn_mfma_f32_16x16x16_bf16)
#define HAVE_MFMA1616 1
__device__ __forceinline__ f32x4 mfma_k16(short4v a, short4v b, f32x4 c) {
    return __builtin_amdgcn_mfma_f32_16x16x16_bf16(
        __builtin_bit_cast(bf16x4, a), __builtin_bit_cast(bf16x4, b), c, 0, 0, 0);
}
#elif __has_builtin(__builtin_amdgcn_mfma_f32_16x16x16bf16_1k)
#define HAVE_MFMA1616 1
__device__ __forceinline__ f32x4 mfma_k16(short4v a, short4v b, f32x4 c) {
    return __builtin_amdgcn_mfma_f32_16x16x16bf16_1k(a, b, c, 0, 0, 0);
}
#else
#define HAVE_MFMA1616 0
#endif
// async global->LDS, 16B/lane; dst = uniform base + lane*16 (m97 pattern)
__device__ __forceinline__ void stage16(const u16* g, u16* l, int lane) {
#if __has_builtin(__builtin_amdgcn_global_load_lds)
    __builtin_amdgcn_global_load_lds(
        (const __attribute__((address_space(1))) unsigned int*)g,
        (__attribute__((address_space(3))) unsigned int*)l, 16, 0, 0);
#else
    *(short8*)(l + lane * 8) = *(const short8*)g;
#endif
}

// ---------------- RMSNorm over tokens: [4096,1024] f32 -> bf16 ----------------
__global__ __launch_bounds__(256) void k_rmsnorm(const float* __restrict__ tokens,
                                                 const float* __restrict__ norm_w,
                                                 u16* __restrict__ xb) {
    const int row = blockIdx.x;
    const int tid = threadIdx.x;
    const float* xp = tokens + (size_t)row * DDIM + tid * 4;
    float4 raw = *(const float4*)xp;
    float ss = raw.x * raw.x + raw.y * raw.y + raw.z * raw.z + raw.w * raw.w;
#pragma unroll
    for (int d = 1; d < 64; d <<= 1) ss += __shfl_xor(ss, d);
    __shared__ float red[4];
    if ((tid & 63) == 0) red[tid >> 6] = ss;
    __syncthreads();
    float tot = red[0] + red[1] + red[2] + red[3];
    float r = rsqrtf(tot * (1.0f / 1024.0f) + 1.1920929e-7f);
    float4 wv = *(const float4*)(norm_w + tid * 4);
    ushort4 o;
    o.x = f2b(raw.x * r * wv.x);
    o.y = f2b(raw.y * r * wv.y);
    o.z = f2b(raw.z * r * wv.z);
    o.w = f2b(raw.w * r * wv.w);
    *(ushort4*)(xb + (size_t)row * DDIM + tid * 4) = o;
}

// ---------------- transpose f32 [R,C] -> bf16 [C,R] ----------------
__global__ __launch_bounds__(256) void k_transpose(const float* __restrict__ in,
                                                   u16* __restrict__ out, int R, int C) {
    __shared__ u16 tile[32][33];
    const int bc = blockIdx.x * 32, br = blockIdx.y * 32;
    const int tx = threadIdx.x & 31, ty = threadIdx.x >> 5;
#pragma unroll
    for (int i = 0; i < 32; i += 8) tile[ty + i][tx] = f2b(in[(size_t)(br + ty + i) * C + bc + tx]);
    __syncthreads();
#pragma unroll
    for (int i = 0; i < 32; i += 8) out[(size_t)(bc + ty + i) * R + br + tx] = tile[tx][ty + i];
}

// ---------------- GEMM: C[M,N] = A[M,K](bf16) x Bt[N,K](bf16), 64x128 tile, async staging ----------------
template <typename OT>
__global__ __launch_bounds__(256) void k_gemm_bt(const u16* __restrict__ A,
                                                 const u16* __restrict__ Bt,
                                                 OT* __restrict__ C,
                                                 int M, int Ncols, int K) {
    __shared__ __attribute__((aligned(16))) u16 As[64 * 32];
    __shared__ __attribute__((aligned(16))) u16 Bs[128 * 32];
    const int tid = threadIdx.x;
    const int lane = tid & 63;
    const int w = tid >> 6;
    const int m0 = blockIdx.y * 64;
    const int n0 = blockIdx.x * 128;
    const int lr = lane & 15;
    const int lq = lane >> 4;

    const u16* aSrc = A + (size_t)(m0 + w * 16 + (lane >> 2)) * K + (lane & 3) * 8;
    const u16* bSrc = Bt + (size_t)(n0 + w * 32 + (lane >> 2)) * K + (lane & 3) * 8;
    u16* aDst = As + w * 16 * 32;
    u16* bDst = Bs + w * 32 * 32;

    f32x4 acc[8];
#pragma unroll
    for (int i = 0; i < 8; i++) acc[i] = (f32x4){0.f, 0.f, 0.f, 0.f};

    for (int k0 = 0; k0 < K; k0 += 32) {
        __syncthreads();
        stage16(aSrc, aDst, lane);
        stage16(bSrc, bDst, lane);
        stage16(bSrc + (size_t)16 * K, bDst + 512, lane);
        aSrc += 32;
        bSrc += 32;
        __syncthreads();
        short8 a = *(const short8*)&As[(w * 16 + lr) * 32 + lq * 8];
#pragma unroll
        for (int nt = 0; nt < 8; ++nt) {
            short8 b = *(const short8*)&Bs[(nt * 16 + lr) * 32 + lq * 8];
            acc[nt] = mfma16(a, b, acc[nt]);
        }
    }
#pragma unroll
    for (int nt = 0; nt < 8; ++nt)
#pragma unroll
        for (int r = 0; r < 4; ++r) {
            int row = m0 + w * 16 + lq * 4 + r;
            int col = n0 + nt * 16 + lr;
            if constexpr (std::is_same_v<OT, u16>)
                C[(size_t)row * Ncols + col] = f2b(acc[nt][r]);
            else
                C[(size_t)row * Ncols + col] = acc[nt][r];
        }
}

// ---------------- per-head L2 norm + scale; emit qn [b,qh,n,dh], kn [b,h,n,dh], vt [b,h,dh,n] ----------------
__global__ __launch_bounds__(256) void k_headnorm(const u16* __restrict__ q_raw,
                                                  const u16* __restrict__ kv_raw,
                                                  const float* __restrict__ q_gamma,
                                                  const float* __restrict__ k_gamma,
                                                  u16* __restrict__ qn,
                                                  u16* __restrict__ kn,
                                                  u16* __restrict__ vt) {
    const int row = blockIdx.x;  // b*N + n
    const int b = row >> 11, n = row & 2047;
    const int lane = threadIdx.x & 63, w = threadIdx.x >> 6;
    const u16* qr = q_raw + (size_t)row * 1024;
    const u16* kvr = kv_raw + (size_t)row * 1024;
#pragma unroll
    for (int t = 0; t < 4; ++t) {
        int qh = w * 4 + t;
        float v = b2f(qr[qh * 64 + lane]);
        float ss = v * v;
#pragma unroll
        for (int d = 1; d < 64; d <<= 1) ss += __shfl_xor(ss, d);
        float nrm = fmaxf(sqrtf(ss), 1e-12f);
        float g = q_gamma[qh * 64 + lane];
        qn[((size_t)(b * QHH + qh) * NN + n) * 64 + lane] = f2b(v / nrm * (g + 1.0f) * 8.0f);
    }
#pragma unroll
    for (int t = 0; t < 2; ++t) {
        int kh = w * 2 + t;
        float v = b2f(kvr[kh * 64 + lane]);
        float ss = v * v;
#pragma unroll
        for (int d = 1; d < 64; d <<= 1) ss += __shfl_xor(ss, d);
        float nrm = fmaxf(sqrtf(ss), 1e-12f);
        float g = k_gamma[kh * 64 + lane];
        kn[((size_t)(b * HH + kh) * NN + n) * 64 + lane] = f2b(v / nrm * (g + 1.0f) * 8.0f);
        float vv = b2f(kvr[512 + kh * 64 + lane]);
        vt[((size_t)(b * HH + kh) * 64 + lane) * NN + n] = f2b(vv);
    }
}

// ---------------- flash attention v7: OPERAND-SWAP — S^T = K·Q^T so softmax output (P^T,
// C-layout) is directly the B-operand of a K=16 MFMA: PV needs NO LDS round-trip, no fences.
// O^T = V^T·P^T accumulated in C-layout [d][i]. 1 wave per block; fixed-max softmax;
// poly-tanh (1 trans/score); K double-buffer (named); LPT dispatch. Output OT[b,qh][64][NN]. ----------------
__global__ __launch_bounds__(64) void k_attn(const u16* __restrict__ qn,
                                             const u16* __restrict__ kn,
                                             const u16* __restrict__ vt,
                                             u16* __restrict__ OT) {
    const int bq = blockIdx.x;  // b*16+qh
    const int b = bq >> 4, qh = bq & 15;
    const int h = qh >> 1;
    const int lane = threadIdx.x;
    const int lr = lane & 15, lq = lane >> 4;
    const int s = 127 - blockIdx.y;  // LPT: heaviest strip dispatched first
    const int i0 = s * 16;

    const u16* Qp = qn + (size_t)(b * QHH + qh) * NN * 64;
    const u16* Kp = kn + (size_t)(b * HH + h) * NN * 64;
    const u16* Vp = vt + (size_t)(b * HH + h) * 64 * NN;
    u16* Op = OT + (size_t)(b * QHH + qh) * 64 * NN;  // O^T: [64 d][NN i]

    // Q fragment: B-operand (n = query i = lane&15), k = d
    short8 qf0 = *(const short8*)&Qp[(size_t)(i0 + lr) * 64 + lq * 8];
    short8 qf1 = *(const short8*)&Qp[(size_t)(i0 + lr) * 64 + 32 + lq * 8];

    f32x4 of[4];  // O^T C-layout: lane holds i=lr, d = dt*16 + lq*4 + r
#pragma unroll
    for (int dt = 0; dt < 4; ++dt) of[dt] = (f32x4){0.f, 0.f, 0.f, 0.f};
    float lsum = 0.f;              // per-lane partial denominator for query row `irow`
    const int irow = i0 + lr;      // this lane's query row (lane-constant!)

    const u16* kq = Kp + (size_t)lr * 64 + lq * 8;  // A-operand: m = key j = lane&15
    const int ntile = (i0 >> 6) + 1;

#if !HAVE_MFMA1616
    __shared__ __attribute__((aligned(16))) u16 pl[16 * 68];  // fallback only
#endif

    short8 kA[8], kB[8];  // named double buffers (R7 lesson: no dynamic indexing!)
    auto loadK = [&](short8(&kf)[8], int jt) {
        const u16* kp = kq + (size_t)jt * 4096;
#pragma unroll
        for (int ct = 0; ct < 4; ++ct) {
            kf[2 * ct] = *(const short8*)&kp[ct * 1024];
            kf[2 * ct + 1] = *(const short8*)&kp[ct * 1024 + 32];
        }
    };

    auto tile = [&](short8(&kf)[8], int jt) {
        const int j0 = jt << 6;
        // ---- V^T fragments for PV (A-operand, K=16): 4 dt x 4 ct, 8B loads ----
        const u16* vp = Vp + (size_t)lr * NN + j0 + lq * 4;
        short4v vf[4][4];
#pragma unroll
        for (int dt = 0; dt < 4; ++dt)
#pragma unroll
            for (int ct = 0; ct < 4; ++ct)
                vf[dt][ct] = *(const short4v*)&vp[(size_t)dt * 16 * NN + ct * 16];
        // ---- S^T = K·Q^T: C-layout lane holds (j = j0+ct*16+lq*4+r, i = irow) ----
        f32x4 sc[4];
#pragma unroll
        for (int ct = 0; ct < 4; ++ct) {
            f32x4 t = (f32x4){0.f, 0.f, 0.f, 0.f};
            t = mfma16(kf[2 * ct], qf0, t);
            t = mfma16(kf[2 * ct + 1], qf1, t);
            sc[ct] = t;
        }
        // ---- softcap+softmax, fixed max 6.25: p = exp2(9.016844*(tanh(s/50)-1)) ----
        const bool masked = (jt == ntile - 1);
        short4v pk[4];
#pragma unroll
        for (int ct = 0; ct < 4; ++ct) {
#pragma unroll
            for (int r = 0; r < 4; ++r) {
                float x = sc[ct][r] * 0.02f;
                float y = x * x;
                float g = fmaf(y, fmaf(y, fmaf(y, fmaf(y, 0.0052188f, -0.0358520f),
                                               0.1236583f), -0.3312901f), 0.9999061f);
                float p = fastexp2(fmaf(x * g, 9.0168440f, -9.0168440f));
                if (masked) {
                    int j = j0 + ct * 16 + lq * 4 + r;
                    p = (j <= irow) ? p : 0.0f;
                }
                lsum += p;
                pk[ct][r] = (short)f2b(p);
            }
        }
#if HAVE_MFMA1616
        // ---- PV directly from registers: O^T += V^T_frag · P^T_frag (K=16) ----
#pragma unroll
        for (int dt = 0; dt < 4; ++dt)
#pragma unroll
            for (int ct = 0; ct < 4; ++ct)
                of[dt] = mfma_k16(vf[dt][ct], pk[ct], of[dt]);
#else
        // ---- fallback: P^T -> LDS as P[i][j], read A-frag, O = P·V (then stored as O^T) ----
#pragma unroll
        for (int ct = 0; ct < 4; ++ct)
#pragma unroll
            for (int r = 0; r < 4; ++r)
                pl[lr * 68 + ct * 16 + lq * 4 + r] = (u16)pk[ct][r];
        asm volatile("s_waitcnt lgkmcnt(0)" ::: "memory");
        short8 pf0 = *(const short8*)&pl[lr * 68 + lq * 8];
        short8 pf1 = *(const short8*)&pl[lr * 68 + 32 + lq * 8];
        const u16* vpb = Vp + (size_t)lr * NN + j0 + lq * 8;
#pragma unroll
        for (int dt = 0; dt < 4; ++dt) {
            short8 v0 = *(const short8*)&vpb[(size_t)dt * 16 * NN];
            short8 v1 = *(const short8*)&vpb[(size_t)dt * 16 * NN + 32];
            of[dt] = mfma16(pf0, v0, of[dt]);
            of[dt] = mfma16(pf1, v1, of[dt]);
        }
#endif
    };

    loadK(kA, 0);
    int jt = 0;
    while (true) {
        if (jt + 1 < ntile) loadK(kB, jt + 1);
        tile(kA, jt);
        if (++jt >= ntile) break;
        if (jt + 1 < ntile) loadK(kA, jt + 1);
        tile(kB, jt);
        if (++jt >= ntile) break;
    }

    // denominator: lanes {lr, lr+16, lr+32, lr+48} share query row irow
    lsum += __shfl_xor(lsum, 16);
    lsum += __shfl_xor(lsum, 32);
#if HAVE_MFMA1616
    const float inv = fastrcp(lsum);
#pragma unroll
    for (int dt = 0; dt < 4; ++dt)
#pragma unroll
        for (int r = 0; r < 4; ++r)
            Op[(size_t)(dt * 16 + lq * 4 + r) * NN + irow] = f2b(of[dt][r] * inv);
#else
    // fallback: of is O[i][d] C-layout (i = lq*4+r rows, d = lane&15); lsum lives at lane lr=i
#pragma unroll
    for (int r = 0; r < 4; ++r) {
        float invr = fastrcp(__shfl(lsum, lq * 4 + r));
#pragma unroll
        for (int dt = 0; dt < 4; ++dt)
            Op[(size_t)(dt * 16 + lr) * NN + i0 + lq * 4 + r] = f2b(of[dt][r] * invr);
    }
#endif
}

// ---------------- combine groups from O^T and transpose: AO[b,n,hh*64+d] = sum_g OT[b,2hh+g][d][n] ----------------
__global__ __launch_bounds__(256) void k_gsum(const u16* __restrict__ OT, u16* __restrict__ AO) {
    __shared__ u16 t[32][34];
    const int b = blockIdx.z;
    const int n0 = blockIdx.x * 32;
    const int c0 = blockIdx.y * 32;  // c = hh*64 + d; 32-tiles never straddle a head boundary
    const int hh = c0 >> 6, d0 = c0 & 63;
    const int tx = threadIdx.x & 31, ty = threadIdx.x >> 5;
    const u16* O0 = OT + ((size_t)(b * QHH + 2 * hh) * 64 + d0) * NN;
    const u16* O1 = OT + ((size_t)(b * QHH + 2 * hh + 1) * 64 + d0) * NN;
#pragma unroll
    for (int i = ty; i < 32; i += 8)
        t[i][tx] = f2b(b2f(O0[(size_t)i * NN + n0 + tx]) + b2f(O1[(size_t)i * NN + n0 + tx]));
    __syncthreads();
#pragma unroll
    for (int i = ty; i < 32; i += 8)
        AO[((size_t)(b * NN) + n0 + i) * 512 + c0 + tx] = t[tx][i];
}

extern "C" void kernel_launch(void* const* d_in, const int* in_sizes, int n_in,
                              void* d_out, int out_size, void* d_ws, size_t ws_size,
                              hipStream_t stream) {
    const float* tokens = (const float*)d_in[0];
    const float* norm_w = (const float*)d_in[1];
    const float* Wq = (const float*)d_in[2];
    const float* Wkv = (const float*)d_in[3];
    const float* Wout = (const float*)d_in[4];
    const float* q_gamma = (const float*)d_in[5];
    const float* k_gamma = (const float*)d_in[6];
    float* out = (float*)d_out;

    char* ws = (char*)d_ws;
    u16* xb = (u16*)(ws + 0);             // 8 MB  [4096,1024]
    u16* WqT = (u16*)(ws + 8388608);      // 2 MB
    u16* WkvT = (u16*)(ws + 10485760);    // 2 MB
    u16* WoutT = (u16*)(ws + 12582912);   // 1 MB
    u16* q_raw = (u16*)(ws + 13631488);   // 8 MB
    u16* kv_raw = (u16*)(ws + 22020096);  // 8 MB
    u16* kn = (u16*)(ws + 30408704);      // 4 MB
    u16* vtb = (u16*)(ws + 34603008);     // 4 MB
    // total 38,797,312 B. Lifetime aliases (stream-ordered, no overlap):
    u16* qn = xb;       // xb dead after QKV GEMMs
    u16* Obuf = q_raw;  // q_raw dead after headnorm; holds O^T (32 heads x 64 x 2048 = 8 MB)
    u16* AO = kv_raw;   // kv_raw dead after headnorm

    k_rmsnorm<<<4096, 256, 0, stream>>>(tokens, norm_w, xb);
    k_transpose<<<dim3(32, 32), 256, 0, stream>>>(Wq, WqT, 1024, 1024);
    k_transpose<<<dim3(32, 32), 256, 0, stream>>>(Wkv, WkvT, 1024, 1024);
    k_transpose<<<dim3(32, 16), 256, 0, stream>>>(Wout, WoutT, 512, 1024);
    k_gemm_bt<u16><<<dim3(8, 64), 256, 0, stream>>>(xb, WqT, q_raw, 4096, 1024, 1024);
    k_gemm_bt<u16><<<dim3(8, 64), 256, 0, stream>>>(xb, WkvT, kv_raw, 4096, 1024, 1024);
    k_headnorm<<<4096, 256, 0, stream>>>(q_raw, kv_raw, q_gamma, k_gamma, qn, kn, vtb);
    k_attn<<<dim3(32, 128), 64, 0, stream>>>(qn, kn, vtb, Obuf);
    k_gsum<<<dim3(64, 16, 2), 256, 0, stream>>>(Obuf, AO);
    k_gemm_bt<float><<<dim3(8, 64), 256, 0, stream>>>(AO, WoutT, out, 4096, 1024, 512);
}

// Round 10
// 210.280 us; speedup vs baseline: 1.6599x; 1.6599x over previous
//
#include <hip/hip_runtime.h>
#include <hip/hip_bf16.h>
#include <type_traits>

typedef unsigned short u16;
typedef __attribute__((ext_vector_type(4))) float f32x4;
typedef __attribute__((ext_vector_type(8))) short short8;
typedef __attribute__((ext_vector_type(4))) short short4v;
typedef __attribute__((ext_vector_type(8))) __bf16 bf16x8;
typedef __attribute__((ext_vector_type(4))) __bf16 bf16x4;

#define BB 2
#define NN 2048
#define DDIM 1024
#define HH 8
#define QHH 16
#define DHH 64

__device__ __forceinline__ float b2f(u16 v) {
    return __builtin_bit_cast(float, ((unsigned)v) << 16);
}
__device__ __forceinline__ u16 f2b(float f) {
    unsigned u = __builtin_bit_cast(unsigned, f);
    u += 0x7FFFu + ((u >> 16) & 1u);   // RNE
    return (u16)(u >> 16);
}
__device__ __forceinline__ float fastrcp(float x) {
#if __has_builtin(__builtin_amdgcn_rcpf)
    return __builtin_amdgcn_rcpf(x);
#else
    return 1.0f / x;
#endif
}
__device__ __forceinline__ float fastexp2(float x) {
#if __has_builtin(__builtin_amdgcn_exp2f)
    return __builtin_amdgcn_exp2f(x);  // v_exp_f32; NB: __exp2f collides with glibc
#else
    return exp2f(x);
#endif
}
__device__ __forceinline__ f32x4 mfma16(short8 a, short8 b, f32x4 c) {
    return __builtin_amdgcn_mfma_f32_16x16x32_bf16(
        __builtin_bit_cast(bf16x8, a), __builtin_bit_cast(bf16x8, b), c, 0, 0, 0);
}
// K=16 MFMA: P^T (C-layout of S^T) is directly the B-operand (verified R9: passed, LDS=0)
#if __has_builtin(__builtin_amdgcn_mfma_f32_16x16x16_bf16)
__device__ __forceinline__ f32x4 mfma_k16(short4v a, short4v b, f32x4 c) {
    return __builtin_amdgcn_mfma_f32_16x16x16_bf16(
        __builtin_bit_cast(bf16x4, a), __builtin_bit_cast(bf16x4, b), c, 0, 0, 0);
}
#else
__device__ __forceinline__ f32x4 mfma_k16(short4v a, short4v b, f32x4 c) {
    return __builtin_amdgcn_mfma_f32_16x16x16bf16_1k(a, b, c, 0, 0, 0);
}
#endif
// async global->LDS, 16B/lane; dst = WAVE-UNIFORM base + lane*16 (m97 pattern)
__device__ __forceinline__ void stage16(const u16* g, u16* l, int lane) {
#if __has_builtin(__builtin_amdgcn_global_load_lds)
    __builtin_amdgcn_global_load_lds(
        (const __attribute__((address_space(1))) unsigned int*)g,
        (__attribute__((address_space(3))) unsigned int*)l, 16, 0, 0);
#else
    *(short8*)(l + lane * 8) = *(const short8*)g;
#endif
}

// ---------------- RMSNorm over tokens: [4096,1024] f32 -> bf16 ----------------
__global__ __launch_bounds__(256) void k_rmsnorm(const float* __restrict__ tokens,
                                                 const float* __restrict__ norm_w,
                                                 u16* __restrict__ xb) {
    const int row = blockIdx.x;
    const int tid = threadIdx.x;
    const float* xp = tokens + (size_t)row * DDIM + tid * 4;
    float4 raw = *(const float4*)xp;
    float ss = raw.x * raw.x + raw.y * raw.y + raw.z * raw.z + raw.w * raw.w;
#pragma unroll
    for (int d = 1; d < 64; d <<= 1) ss += __shfl_xor(ss, d);
    __shared__ float red[4];
    if ((tid & 63) == 0) red[tid >> 6] = ss;
    __syncthreads();
    float tot = red[0] + red[1] + red[2] + red[3];
    float r = rsqrtf(tot * (1.0f / 1024.0f) + 1.1920929e-7f);
    float4 wv = *(const float4*)(norm_w + tid * 4);
    ushort4 o;
    o.x = f2b(raw.x * r * wv.x);
    o.y = f2b(raw.y * r * wv.y);
    o.z = f2b(raw.z * r * wv.z);
    o.w = f2b(raw.w * r * wv.w);
    *(ushort4*)(xb + (size_t)row * DDIM + tid * 4) = o;
}

// ---------------- transpose f32 [R,C] -> bf16 [C,R] ----------------
__global__ __launch_bounds__(256) void k_transpose(const float* __restrict__ in,
                                                   u16* __restrict__ out, int R, int C) {
    __shared__ u16 tile[32][33];
    const int bc = blockIdx.x * 32, br = blockIdx.y * 32;
    const int tx = threadIdx.x & 31, ty = threadIdx.x >> 5;
#pragma unroll
    for (int i = 0; i < 32; i += 8) tile[ty + i][tx] = f2b(in[(size_t)(br + ty + i) * C + bc + tx]);
    __syncthreads();
#pragma unroll
    for (int i = 0; i < 32; i += 8) out[(size_t)(bc + ty + i) * R + br + tx] = tile[tx][ty + i];
}

// ---------------- GEMM: C[M,N] = A[M,K](bf16) x Bt[N,K](bf16), 64x128 tile, async staging ----------------
template <typename OT>
__global__ __launch_bounds__(256) void k_gemm_bt(const u16* __restrict__ A,
                                                 const u16* __restrict__ Bt,
                                                 OT* __restrict__ C,
                                                 int M, int Ncols, int K) {
    __shared__ __attribute__((aligned(16))) u16 As[64 * 32];
    __shared__ __attribute__((aligned(16))) u16 Bs[128 * 32];
    const int tid = threadIdx.x;
    const int lane = tid & 63;
    const int w = tid >> 6;
    const int m0 = blockIdx.y * 64;
    const int n0 = blockIdx.x * 128;
    const int lr = lane & 15;
    const int lq = lane >> 4;

    const u16* aSrc = A + (size_t)(m0 + w * 16 + (lane >> 2)) * K + (lane & 3) * 8;
    const u16* bSrc = Bt + (size_t)(n0 + w * 32 + (lane >> 2)) * K + (lane & 3) * 8;
    u16* aDst = As + w * 16 * 32;
    u16* bDst = Bs + w * 32 * 32;

    f32x4 acc[8];
#pragma unroll
    for (int i = 0; i < 8; i++) acc[i] = (f32x4){0.f, 0.f, 0.f, 0.f};

    for (int k0 = 0; k0 < K; k0 += 32) {
        __syncthreads();
        stage16(aSrc, aDst, lane);
        stage16(bSrc, bDst, lane);
        stage16(bSrc + (size_t)16 * K, bDst + 512, lane);
        aSrc += 32;
        bSrc += 32;
        __syncthreads();
        short8 a = *(const short8*)&As[(w * 16 + lr) * 32 + lq * 8];
#pragma unroll
        for (int nt = 0; nt < 8; ++nt) {
            short8 b = *(const short8*)&Bs[(nt * 16 + lr) * 32 + lq * 8];
            acc[nt] = mfma16(a, b, acc[nt]);
        }
    }
#pragma unroll
    for (int nt = 0; nt < 8; ++nt)
#pragma unroll
        for (int r = 0; r < 4; ++r) {
            int row = m0 + w * 16 + lq * 4 + r;
            int col = n0 + nt * 16 + lr;
            if constexpr (std::is_same_v<OT, u16>)
                C[(size_t)row * Ncols + col] = f2b(acc[nt][r]);
            else
                C[(size_t)row * Ncols + col] = acc[nt][r];
        }
}

// ---------------- per-head L2 norm + scale; emit qn [b,qh,n,dh], kn [b,h,n,dh], vt [b,h,dh,n] ----------------
__global__ __launch_bounds__(256) void k_headnorm(const u16* __restrict__ q_raw,
                                                  const u16* __restrict__ kv_raw,
                                                  const float* __restrict__ q_gamma,
                                                  const float* __restrict__ k_gamma,
                                                  u16* __restrict__ qn,
                                                  u16* __restrict__ kn,
                                                  u16* __restrict__ vt) {
    const int row = blockIdx.x;  // b*N + n
    const int b = row >> 11, n = row & 2047;
    const int lane = threadIdx.x & 63, w = threadIdx.x >> 6;
    const u16* qr = q_raw + (size_t)row * 1024;
    const u16* kvr = kv_raw + (size_t)row * 1024;
#pragma unroll
    for (int t = 0; t < 4; ++t) {
        int qh = w * 4 + t;
        float v = b2f(qr[qh * 64 + lane]);
        float ss = v * v;
#pragma unroll
        for (int d = 1; d < 64; d <<= 1) ss += __shfl_xor(ss, d);
        float nrm = fmaxf(sqrtf(ss), 1e-12f);
        float g = q_gamma[qh * 64 + lane];
        qn[((size_t)(b * QHH + qh) * NN + n) * 64 + lane] = f2b(v / nrm * (g + 1.0f) * 8.0f);
    }
#pragma unroll
    for (int t = 0; t < 2; ++t) {
        int kh = w * 2 + t;
        float v = b2f(kvr[kh * 64 + lane]);
        float ss = v * v;
#pragma unroll
        for (int d = 1; d < 64; d <<= 1) ss += __shfl_xor(ss, d);
        float nrm = fmaxf(sqrtf(ss), 1e-12f);
        float g = k_gamma[kh * 64 + lane];
        kn[((size_t)(b * HH + kh) * NN + n) * 64 + lane] = f2b(v / nrm * (g + 1.0f) * 8.0f);
        float vv = b2f(kvr[512 + kh * 64 + lane]);
        vt[((size_t)(b * HH + kh) * 64 + lane) * NN + n] = f2b(vv);
    }
}

// ---------------- flash attention v8: FA2-style block-cooperative LDS staging.
// Block = 4 waves x 16 rows = 64 query rows of one (b,qh). All 4 waves share the SAME
// j-tiles (ntile = z+1 uniform; mask handles diagonal), so K/V tiles are staged ONCE
// per block via coalesced global_load_lds (16B/lane), double-buffered, 1 barrier/tile
// with prefetch issued after the barrier (drain hits a tile-old request).
// Math = R9 (verified): S^T = K·Q^T; P^T (C-layout) feeds K=16 PV directly from regs;
// fixed-max softmax (softcap bounds |s_cap| <= 6.25); poly-tanh, 1 trans/score.
// XOR-16B-chunk swizzle on staging SOURCE spreads LDS banks (dst stays contiguous). ----------------
__global__ __launch_bounds__(256) void k_attn(const u16* __restrict__ qn,
                                              const u16* __restrict__ kn,
                                              const u16* __restrict__ vt,
                                              u16* __restrict__ OT) {
    const int bq = blockIdx.x;  // b*16+qh
    const int b = bq >> 4, qh = bq & 15;
    const int h = qh >> 1;
    const int tid = threadIdx.x;
    const int lane = tid & 63, w = tid >> 6;
    const int lr = lane & 15, lq = lane >> 4;
    const int z = 31 - blockIdx.y;   // LPT: heaviest strips (most tiles) dispatched first
    const int i0 = z * 64 + w * 16;  // this wave's 16 query rows
    const int ntile = z + 1;         // same for all 4 waves (64-row block, 64-col tiles)

    const u16* Qp = qn + (size_t)(b * QHH + qh) * NN * 64;
    const u16* Kp = kn + (size_t)(b * HH + h) * NN * 64;
    const u16* Vp = vt + (size_t)(b * HH + h) * 64 * NN;
    u16* Op = OT + (size_t)(b * QHH + qh) * 64 * NN;  // O^T: [64 d][NN i]

    // 64x64 bf16 tiles, double-buffered: 4 x 8 KB = 32 KB
    __shared__ __attribute__((aligned(16))) u16 Ks[2][64 * 64];
    __shared__ __attribute__((aligned(16))) u16 Vs[2][64 * 64];

    // Q B-fragment (n = query row i0+lr, k = d): one-time scattered load, amortized
    short8 qf0 = *(const short8*)&Qp[(size_t)(i0 + lr) * 64 + lq * 8];
    short8 qf1 = *(const short8*)&Qp[(size_t)(i0 + lr) * 64 + 32 + lq * 8];

    f32x4 of[4];  // O^T C-layout: lane holds i = lr, d = dt*16 + lq*4 + r
#pragma unroll
    for (int dt = 0; dt < 4; ++dt) of[dt] = (f32x4){0.f, 0.f, 0.f, 0.f};
    float lsum = 0.f;
    const int irow = i0 + lr;  // lane-constant query row

    // staging lane geometry: lane covers row (base + lane>>3), source 16B-chunk
    // (lane&7)^(lane>>3) -> stored chunk (lane&7): XOR swizzle lives on the source side
    const int srow = lane >> 3;
    const int sch = (lane ^ srow) & 7;
    const int rA = w * 16, rB = w * 16 + 8;  // each wave stages 16 of the 64 rows (2 calls each)

    auto stageKV = [&](int buf, int jt) {
        const int j0 = jt << 6;
        stage16(Kp + (size_t)(j0 + rA + srow) * 64 + sch * 8, &Ks[buf][rA * 64], lane);
        stage16(Kp + (size_t)(j0 + rB + srow) * 64 + sch * 8, &Ks[buf][rB * 64], lane);
        stage16(Vp + (size_t)(rA + srow) * NN + j0 + sch * 8, &Vs[buf][rA * 64], lane);
        stage16(Vp + (size_t)(rB + srow) * NN + j0 + sch * 8, &Vs[buf][rB * 64], lane);
    };

    auto tile = [&](int buf, int jt) {
        const int j0 = jt << 6;
        const u16* kb = &Ks[buf][0];
        const u16* vb = &Vs[buf][0];
        // ---- S^T = K·Q^T: A-operand K[j = ct*16+lr][d], swizzled chunk = (half*4+lq)^(lr&7) ----
        f32x4 sc[4];
#pragma unroll
        for (int ct = 0; ct < 4; ++ct) {
            const int r = ct * 16 + lr;
            short8 kf0 = *(const short8*)&kb[r * 64 + ((lq ^ (lr & 7)) << 3)];
            short8 kf1 = *(const short8*)&kb[r * 64 + (((4 + lq) ^ (lr & 7)) << 3)];
            f32x4 t = (f32x4){0.f, 0.f, 0.f, 0.f};
            t = mfma16(kf0, qf0, t);
            t = mfma16(kf1, qf1, t);
            sc[ct] = t;
        }
        // ---- softcap+softmax, fixed max 6.25: p = exp2(9.016844*(tanh(s/50)-1)) ----
        const bool masked = (jt == ntile - 1);
        short4v pk[4];
#pragma unroll
        for (int ct = 0; ct < 4; ++ct) {
#pragma unroll
            for (int r = 0; r < 4; ++r) {
                float x = sc[ct][r] * 0.02f;
                float y = x * x;
                float g = fmaf(y, fmaf(y, fmaf(y, fmaf(y, 0.0052188f, -0.0358520f),
                                               0.1236583f), -0.3312901f), 0.9999061f);
                float p = fastexp2(fmaf(x * g, 9.0168440f, -9.0168440f));
                if (masked) {
                    int j = j0 + ct * 16 + lq * 4 + r;
                    p = (j <= irow) ? p : 0.0f;
                }
                lsum += p;
                pk[ct][r] = (short)f2b(p);
            }
        }
        // ---- PV from registers+LDS: O^T += V^T_frag · P^T_frag (K=16) ----
        // V^T[d = dt*16+lr][j = ct*16 + lq*4 ..+4]: chunk16 = (ct*2 + (lq>>1)) ^ (lr&7)
#pragma unroll
        for (int dt = 0; dt < 4; ++dt) {
            const int d = dt * 16 + lr;
#pragma unroll
            for (int ct = 0; ct < 4; ++ct) {
                short4v vf = *(const short4v*)
                    &vb[d * 64 + ((((ct << 1) + (lq >> 1)) ^ (lr & 7)) << 3) + ((lq & 1) << 2)];
                of[dt] = mfma_k16(vf, pk[ct], of[dt]);
            }
        }
    };

    stageKV(0, 0);
    for (int jt = 0; jt < ntile; ++jt) {
        const int buf = jt & 1;
        __syncthreads();  // buf's staging (issued a full tile ago) complete; buf^1 free
        if (jt + 1 < ntile) stageKV(buf ^ 1, jt + 1);
        tile(buf, jt);
    }

    // denominator: lanes {lr, lr+16, lr+32, lr+48} share query row irow
    lsum += __shfl_xor(lsum, 16);
    lsum += __shfl_xor(lsum, 32);
    const float inv = fastrcp(lsum);
#pragma unroll
    for (int dt = 0; dt < 4; ++dt)
#pragma unroll
        for (int r = 0; r < 4; ++r)
            Op[(size_t)(dt * 16 + lq * 4 + r) * NN + irow] = f2b(of[dt][r] * inv);
}

// ---------------- combine groups from O^T and transpose: AO[b,n,hh*64+d] = sum_g OT[b,2hh+g][d][n] ----------------
__global__ __launch_bounds__(256) void k_gsum(const u16* __restrict__ OT, u16* __restrict__ AO) {
    __shared__ u16 t[32][34];
    const int b = blockIdx.z;
    const int n0 = blockIdx.x * 32;
    const int c0 = blockIdx.y * 32;  // c = hh*64 + d; 32-tiles never straddle a head boundary
    const int hh = c0 >> 6, d0 = c0 & 63;
    const int tx = threadIdx.x & 31, ty = threadIdx.x >> 5;
    const u16* O0 = OT + ((size_t)(b * QHH + 2 * hh) * 64 + d0) * NN;
    const u16* O1 = OT + ((size_t)(b * QHH + 2 * hh + 1) * 64 + d0) * NN;
#pragma unroll
    for (int i = ty; i < 32; i += 8)
        t[i][tx] = f2b(b2f(O0[(size_t)i * NN + n0 + tx]) + b2f(O1[(size_t)i * NN + n0 + tx]));
    __syncthreads();
#pragma unroll
    for (int i = ty; i < 32; i += 8)
        AO[((size_t)(b * NN) + n0 + i) * 512 + c0 + tx] = t[tx][i];
}

extern "C" void kernel_launch(void* const* d_in, const int* in_sizes, int n_in,
                              void* d_out, int out_size, void* d_ws, size_t ws_size,
                              hipStream_t stream) {
    const float* tokens = (const float*)d_in[0];
    const float* norm_w = (const float*)d_in[1];
    const float* Wq = (const float*)d_in[2];
    const float* Wkv = (const float*)d_in[3];
    const float* Wout = (const float*)d_in[4];
    const float* q_gamma = (const float*)d_in[5];
    const float* k_gamma = (const float*)d_in[6];
    float* out = (float*)d_out;

    char* ws = (char*)d_ws;
    u16* xb = (u16*)(ws + 0);             // 8 MB  [4096,1024]
    u16* WqT = (u16*)(ws + 8388608);      // 2 MB
    u16* WkvT = (u16*)(ws + 10485760);    // 2 MB
    u16* WoutT = (u16*)(ws + 12582912);   // 1 MB
    u16* q_raw = (u16*)(ws + 13631488);   // 8 MB
    u16* kv_raw = (u16*)(ws + 22020096);  // 8 MB
    u16* kn = (u16*)(ws + 30408704);      // 4 MB
    u16* vtb = (u16*)(ws + 34603008);     // 4 MB
    // total 38,797,312 B. Lifetime aliases (stream-ordered, no overlap):
    u16* qn = xb;       // xb dead after QKV GEMMs
    u16* Obuf = q_raw;  // q_raw dead after headnorm; holds O^T (32 heads x 64 x 2048 = 8 MB)
    u16* AO = kv_raw;   // kv_raw dead after headnorm

    k_rmsnorm<<<4096, 256, 0, stream>>>(tokens, norm_w, xb);
    k_transpose<<<dim3(32, 32), 256, 0, stream>>>(Wq, WqT, 1024, 1024);
    k_transpose<<<dim3(32, 32), 256, 0, stream>>>(Wkv, WkvT, 1024, 1024);
    k_transpose<<<dim3(32, 16), 256, 0, stream>>>(Wout, WoutT, 512, 1024);
    k_gemm_bt<u16><<<dim3(8, 64), 256, 0, stream>>>(xb, WqT, q_raw, 4096, 1024, 1024);
    k_gemm_bt<u16><<<dim3(8, 64), 256, 0, stream>>>(xb, WkvT, kv_raw, 4096, 1024, 1024);
    k_headnorm<<<4096, 256, 0, stream>>>(q_raw, kv_raw, q_gamma, k_gamma, qn, kn, vtb);
    k_attn<<<dim3(32, 32), 256, 0, stream>>>(qn, kn, vtb, Obuf);
    k_gsum<<<dim3(64, 16, 2), 256, 0, stream>>>(Obuf, AO);
    k_gemm_bt<float><<<dim3(8, 64), 256, 0, stream>>>(AO, WoutT, out, 4096, 1024, 512);
}

// Round 11
// 189.257 us; speedup vs baseline: 1.8442x; 1.1111x over previous
//
#include <hip/hip_runtime.h>
#include <hip/hip_bf16.h>
#include <type_traits>

typedef unsigned short u16;
typedef __attribute__((ext_vector_type(4))) float f32x4;
typedef __attribute__((ext_vector_type(8))) short short8;
typedef __attribute__((ext_vector_type(4))) short short4v;
typedef __attribute__((ext_vector_type(8))) __bf16 bf16x8;
typedef __attribute__((ext_vector_type(4))) __bf16 bf16x4;

#define BB 2
#define NN 2048
#define DDIM 1024
#define HH 8
#define QHH 16
#define DHH 64

__device__ __forceinline__ float b2f(u16 v) {
    return __builtin_bit_cast(float, ((unsigned)v) << 16);
}
__device__ __forceinline__ u16 f2b(float f) {
    unsigned u = __builtin_bit_cast(unsigned, f);
    u += 0x7FFFu + ((u >> 16) & 1u);   // RNE
    return (u16)(u >> 16);
}
__device__ __forceinline__ float fastrcp(float x) {
#if __has_builtin(__builtin_amdgcn_rcpf)
    return __builtin_amdgcn_rcpf(x);
#else
    return 1.0f / x;
#endif
}
__device__ __forceinline__ float fastexp2(float x) {
#if __has_builtin(__builtin_amdgcn_exp2f)
    return __builtin_amdgcn_exp2f(x);  // v_exp_f32; NB: __exp2f collides with glibc
#else
    return exp2f(x);
#endif
}
__device__ __forceinline__ f32x4 mfma16(short8 a, short8 b, f32x4 c) {
    return __builtin_amdgcn_mfma_f32_16x16x32_bf16(
        __builtin_bit_cast(bf16x8, a), __builtin_bit_cast(bf16x8, b), c, 0, 0, 0);
}
// K=16 MFMA: P^T (C-layout of S^T) is directly the B-operand (verified R9/R10)
#if __has_builtin(__builtin_amdgcn_mfma_f32_16x16x16_bf16)
__device__ __forceinline__ f32x4 mfma_k16(short4v a, short4v b, f32x4 c) {
    return __builtin_amdgcn_mfma_f32_16x16x16_bf16(
        __builtin_bit_cast(bf16x4, a), __builtin_bit_cast(bf16x4, b), c, 0, 0, 0);
}
#else
__device__ __forceinline__ f32x4 mfma_k16(short4v a, short4v b, f32x4 c) {
    return __builtin_amdgcn_mfma_f32_16x16x16bf16_1k(a, b, c, 0, 0, 0);
}
#endif
// async global->LDS, 16B/lane; dst = WAVE-UNIFORM base + lane*16 (m97 pattern)
__device__ __forceinline__ void stage16(const u16* g, u16* l, int lane) {
#if __has_builtin(__builtin_amdgcn_global_load_lds)
    __builtin_amdgcn_global_load_lds(
        (const __attribute__((address_space(1))) unsigned int*)g,
        (__attribute__((address_space(3))) unsigned int*)l, 16, 0, 0);
#else
    *(short8*)(l + lane * 8) = *(const short8*)g;
#endif
}

// ---------------- RMSNorm over tokens: [4096,1024] f32 -> bf16 ----------------
__global__ __launch_bounds__(256) void k_rmsnorm(const float* __restrict__ tokens,
                                                 const float* __restrict__ norm_w,
                                                 u16* __restrict__ xb) {
    const int row = blockIdx.x;
    const int tid = threadIdx.x;
    const float* xp = tokens + (size_t)row * DDIM + tid * 4;
    float4 raw = *(const float4*)xp;
    float ss = raw.x * raw.x + raw.y * raw.y + raw.z * raw.z + raw.w * raw.w;
#pragma unroll
    for (int d = 1; d < 64; d <<= 1) ss += __shfl_xor(ss, d);
    __shared__ float red[4];
    if ((tid & 63) == 0) red[tid >> 6] = ss;
    __syncthreads();
    float tot = red[0] + red[1] + red[2] + red[3];
    float r = rsqrtf(tot * (1.0f / 1024.0f) + 1.1920929e-7f);
    float4 wv = *(const float4*)(norm_w + tid * 4);
    ushort4 o;
    o.x = f2b(raw.x * r * wv.x);
    o.y = f2b(raw.y * r * wv.y);
    o.z = f2b(raw.z * r * wv.z);
    o.w = f2b(raw.w * r * wv.w);
    *(ushort4*)(xb + (size_t)row * DDIM + tid * 4) = o;
}

// ---------------- batched weight transpose f32 [R,C] -> bf16 [C,R]; z selects matrix ----------------
__global__ __launch_bounds__(256) void k_wprep(const float* __restrict__ Wq,
                                               const float* __restrict__ Wkv,
                                               const float* __restrict__ Wout,
                                               u16* __restrict__ WqT,
                                               u16* __restrict__ WkvT,
                                               u16* __restrict__ WoutT) {
    const int z = blockIdx.z;
    const float* in = (z == 0) ? Wq : (z == 1) ? Wkv : Wout;
    u16* out = (z == 0) ? WqT : (z == 1) ? WkvT : WoutT;
    const int R = (z == 2) ? 512 : 1024, C = 1024;
    const int br = blockIdx.y * 32;
    if (br >= R) return;
    __shared__ u16 tile[32][33];
    const int bc = blockIdx.x * 32;
    const int tx = threadIdx.x & 31, ty = threadIdx.x >> 5;
#pragma unroll
    for (int i = 0; i < 32; i += 8) tile[ty + i][tx] = f2b(in[(size_t)(br + ty + i) * C + bc + tx]);
    __syncthreads();
#pragma unroll
    for (int i = 0; i < 32; i += 8) out[(size_t)(bc + ty + i) * R + br + tx] = tile[tx][ty + i];
}

// ---------------- GEMM 128x128 (m97-style): C[M,N] = A[M,K] x Bt[N,K], async staging,
// 4 waves x (4x4) 16x16x32 frags = 16 MFMA/wave/k-step ----------------
__global__ __launch_bounds__(256) void k_gemm128(const u16* __restrict__ A,
                                                 const u16* __restrict__ Bt,
                                                 u16* __restrict__ C,
                                                 int M, int Ncols, int K) {
    __shared__ __attribute__((aligned(16))) u16 As[128 * 32];
    __shared__ __attribute__((aligned(16))) u16 Bs[128 * 32];
    const int tid = threadIdx.x;
    const int lane = tid & 63;
    const int w = tid >> 6;
    const int m0 = blockIdx.y * 128;
    const int n0 = blockIdx.x * 128;
    const int wr = (w >> 1) * 64;
    const int wc = (w & 1) * 64;
    const int lr = lane & 15;
    const int lq = lane >> 4;

    // wave w stages rows [w*32, w*32+32) of As and Bs (two 16-row stage16 calls each)
    const int ch0 = w * 32;
    const u16* aSrc = A + (size_t)(m0 + ch0 + (lane >> 2)) * K + (lane & 3) * 8;
    const u16* bSrc = Bt + (size_t)(n0 + ch0 + (lane >> 2)) * K + (lane & 3) * 8;
    u16* aDst = As + ch0 * 32;
    u16* bDst = Bs + ch0 * 32;

    f32x4 acc[4][4];
#pragma unroll
    for (int i = 0; i < 4; i++)
#pragma unroll
        for (int j = 0; j < 4; j++) acc[i][j] = (f32x4){0.f, 0.f, 0.f, 0.f};

    for (int k0 = 0; k0 < K; k0 += 32) {
        __syncthreads();
        stage16(aSrc, aDst, lane);
        stage16(aSrc + (size_t)16 * K, aDst + 512, lane);
        stage16(bSrc, bDst, lane);
        stage16(bSrc + (size_t)16 * K, bDst + 512, lane);
        aSrc += 32;
        bSrc += 32;
        __syncthreads();
        short8 a[4], b[4];
#pragma unroll
        for (int mi = 0; mi < 4; ++mi) a[mi] = *(const short8*)&As[(wr + mi * 16 + lr) * 32 + lq * 8];
#pragma unroll
        for (int ni = 0; ni < 4; ++ni) b[ni] = *(const short8*)&Bs[(wc + ni * 16 + lr) * 32 + lq * 8];
#pragma unroll
        for (int mi = 0; mi < 4; ++mi)
#pragma unroll
            for (int ni = 0; ni < 4; ++ni) acc[mi][ni] = mfma16(a[mi], b[ni], acc[mi][ni]);
    }
#pragma unroll
    for (int mi = 0; mi < 4; ++mi)
#pragma unroll
        for (int ni = 0; ni < 4; ++ni)
#pragma unroll
            for (int r = 0; r < 4; ++r) {
                int row = m0 + wr + mi * 16 + lq * 4 + r;
                int col = n0 + wc + ni * 16 + lr;
                C[(size_t)row * Ncols + col] = f2b(acc[mi][ni][r]);
            }
}

// ---------------- GEMM 64x128: f32 out (final out-proj) ----------------
__global__ __launch_bounds__(256) void k_gemm64f(const u16* __restrict__ A,
                                                 const u16* __restrict__ Bt,
                                                 float* __restrict__ C,
                                                 int M, int Ncols, int K) {
    __shared__ __attribute__((aligned(16))) u16 As[64 * 32];
    __shared__ __attribute__((aligned(16))) u16 Bs[128 * 32];
    const int tid = threadIdx.x;
    const int lane = tid & 63;
    const int w = tid >> 6;
    const int m0 = blockIdx.y * 64;
    const int n0 = blockIdx.x * 128;
    const int lr = lane & 15;
    const int lq = lane >> 4;

    const u16* aSrc = A + (size_t)(m0 + w * 16 + (lane >> 2)) * K + (lane & 3) * 8;
    const u16* bSrc = Bt + (size_t)(n0 + w * 32 + (lane >> 2)) * K + (lane & 3) * 8;
    u16* aDst = As + w * 16 * 32;
    u16* bDst = Bs + w * 32 * 32;

    f32x4 acc[8];
#pragma unroll
    for (int i = 0; i < 8; i++) acc[i] = (f32x4){0.f, 0.f, 0.f, 0.f};

    for (int k0 = 0; k0 < K; k0 += 32) {
        __syncthreads();
        stage16(aSrc, aDst, lane);
        stage16(bSrc, bDst, lane);
        stage16(bSrc + (size_t)16 * K, bDst + 512, lane);
        aSrc += 32;
        bSrc += 32;
        __syncthreads();
        short8 a = *(const short8*)&As[(w * 16 + lr) * 32 + lq * 8];
#pragma unroll
        for (int nt = 0; nt < 8; ++nt) {
            short8 b = *(const short8*)&Bs[(nt * 16 + lr) * 32 + lq * 8];
            acc[nt] = mfma16(a, b, acc[nt]);
        }
    }
#pragma unroll
    for (int nt = 0; nt < 8; ++nt)
#pragma unroll
        for (int r = 0; r < 4; ++r) {
            int row = m0 + w * 16 + lq * 4 + r;
            int col = n0 + nt * 16 + lr;
            C[(size_t)row * Ncols + col] = acc[nt][r];
        }
}

// ---------------- per-head L2 norm + scale from FUSED qkv [4096][2048]; emit qn, kn ----------------
__global__ __launch_bounds__(256) void k_headnorm(const u16* __restrict__ qkv,
                                                  const float* __restrict__ q_gamma,
                                                  const float* __restrict__ k_gamma,
                                                  u16* __restrict__ qn,
                                                  u16* __restrict__ kn) {
    const int row = blockIdx.x;  // b*N + n
    const int b = row >> 11, n = row & 2047;
    const int lane = threadIdx.x & 63, w = threadIdx.x >> 6;
    const u16* qr = qkv + (size_t)row * 2048;
    const u16* kvr = qkv + (size_t)row * 2048 + 1024;
#pragma unroll
    for (int t = 0; t < 4; ++t) {
        int qh = w * 4 + t;
        float v = b2f(qr[qh * 64 + lane]);
        float ss = v * v;
#pragma unroll
        for (int d = 1; d < 64; d <<= 1) ss += __shfl_xor(ss, d);
        float nrm = fmaxf(sqrtf(ss), 1e-12f);
        float g = q_gamma[qh * 64 + lane];
        qn[((size_t)(b * QHH + qh) * NN + n) * 64 + lane] = f2b(v / nrm * (g + 1.0f) * 8.0f);
    }
    {
        int kh = w * 2 + (lane >> 5);  // use 2 half-waves? no — keep simple: loop t=0..1
    }
#pragma unroll
    for (int t = 0; t < 2; ++t) {
        int kh = w * 2 + t;
        float v = b2f(kvr[kh * 64 + lane]);
        float ss = v * v;
#pragma unroll
        for (int d = 1; d < 64; d <<= 1) ss += __shfl_xor(ss, d);
        float nrm = fmaxf(sqrtf(ss), 1e-12f);
        float g = k_gamma[kh * 64 + lane];
        kn[((size_t)(b * HH + kh) * NN + n) * 64 + lane] = f2b(v / nrm * (g + 1.0f) * 8.0f);
    }
}

// ---------------- V transpose via LDS, fully coalesced both sides:
// vt[b,h][d][n] from fused qkv rows (v-part at +1536) ----------------
__global__ __launch_bounds__(256) void k_vtrans(const u16* __restrict__ qkv,
                                                u16* __restrict__ vt) {
    const int bh = blockIdx.x;           // b*8+h
    const int b = bh >> 3, h = bh & 7;
    const int n0 = blockIdx.y * 64;
    const int tid = threadIdx.x;
    __shared__ u16 t[64 * 72];           // row pad 72 keeps 16B-aligned rows, breaks bank stride
#pragma unroll
    for (int it = 0; it < 2; ++it) {
        int idx = tid + it * 256;        // 512 chunks: row i = idx>>3, chunk c = idx&7
        int i = idx >> 3, c = idx & 7;
        short8 v = *(const short8*)&qkv[(size_t)(b * NN + n0 + i) * 2048 + 1536 + h * 64 + c * 8];
        *(short8*)&t[i * 72 + c * 8] = v;
    }
    __syncthreads();
#pragma unroll
    for (int it = 0; it < 2; ++it) {
        int idx = tid + it * 256;        // d = idx>>3, n-chunk c = idx&7
        int d = idx >> 3, c = idx & 7;
        ushort4 a, bvec;
        u16 tmp[8];
#pragma unroll
        for (int j = 0; j < 8; ++j) tmp[j] = t[(c * 8 + j) * 72 + d];
        *(short8*)&vt[((size_t)(bh * 64 + d)) * NN + n0 + c * 8] = *(short8*)tmp;
        (void)a; (void)bvec;
    }
}

// ---------------- flash attention v8 (R10 WIN, unchanged): FA2-style block-cooperative
// LDS staging; S^T = K·Q^T; P^T feeds K=16 PV from regs; fixed-max poly-tanh softmax ----------------
__global__ __launch_bounds__(256) void k_attn(const u16* __restrict__ qn,
                                              const u16* __restrict__ kn,
                                              const u16* __restrict__ vt,
                                              u16* __restrict__ OT) {
    const int bq = blockIdx.x;  // b*16+qh
    const int b = bq >> 4, qh = bq & 15;
    const int h = qh >> 1;
    const int tid = threadIdx.x;
    const int lane = tid & 63, w = tid >> 6;
    const int lr = lane & 15, lq = lane >> 4;
    const int z = 31 - blockIdx.y;   // LPT: heaviest strips first
    const int i0 = z * 64 + w * 16;
    const int ntile = z + 1;

    const u16* Qp = qn + (size_t)(b * QHH + qh) * NN * 64;
    const u16* Kp = kn + (size_t)(b * HH + h) * NN * 64;
    const u16* Vp = vt + (size_t)(b * HH + h) * 64 * NN;
    u16* Op = OT + (size_t)(b * QHH + qh) * 64 * NN;

    __shared__ __attribute__((aligned(16))) u16 Ks[2][64 * 64];
    __shared__ __attribute__((aligned(16))) u16 Vs[2][64 * 64];

    short8 qf0 = *(const short8*)&Qp[(size_t)(i0 + lr) * 64 + lq * 8];
    short8 qf1 = *(const short8*)&Qp[(size_t)(i0 + lr) * 64 + 32 + lq * 8];

    f32x4 of[4];
#pragma unroll
    for (int dt = 0; dt < 4; ++dt) of[dt] = (f32x4){0.f, 0.f, 0.f, 0.f};
    float lsum = 0.f;
    const int irow = i0 + lr;

    const int srow = lane >> 3;
    const int sch = (lane ^ srow) & 7;
    const int rA = w * 16, rB = w * 16 + 8;

    auto stageKV = [&](int buf, int jt) {
        const int j0 = jt << 6;
        stage16(Kp + (size_t)(j0 + rA + srow) * 64 + sch * 8, &Ks[buf][rA * 64], lane);
        stage16(Kp + (size_t)(j0 + rB + srow) * 64 + sch * 8, &Ks[buf][rB * 64], lane);
        stage16(Vp + (size_t)(rA + srow) * NN + j0 + sch * 8, &Vs[buf][rA * 64], lane);
        stage16(Vp + (size_t)(rB + srow) * NN + j0 + sch * 8, &Vs[buf][rB * 64], lane);
    };

    auto tile = [&](int buf, int jt) {
        const int j0 = jt << 6;
        const u16* kb = &Ks[buf][0];
        const u16* vb = &Vs[buf][0];
        f32x4 sc[4];
#pragma unroll
        for (int ct = 0; ct < 4; ++ct) {
            const int r = ct * 16 + lr;
            short8 kf0 = *(const short8*)&kb[r * 64 + ((lq ^ (lr & 7)) << 3)];
            short8 kf1 = *(const short8*)&kb[r * 64 + (((4 + lq) ^ (lr & 7)) << 3)];
            f32x4 t = (f32x4){0.f, 0.f, 0.f, 0.f};
            t = mfma16(kf0, qf0, t);
            t = mfma16(kf1, qf1, t);
            sc[ct] = t;
        }
        const bool masked = (jt == ntile - 1);
        short4v pk[4];
#pragma unroll
        for (int ct = 0; ct < 4; ++ct) {
#pragma unroll
            for (int r = 0; r < 4; ++r) {
                float x = sc[ct][r] * 0.02f;
                float y = x * x;
                float g = fmaf(y, fmaf(y, fmaf(y, fmaf(y, 0.0052188f, -0.0358520f),
                                               0.1236583f), -0.3312901f), 0.9999061f);
                float p = fastexp2(fmaf(x * g, 9.0168440f, -9.0168440f));
                if (masked) {
                    int j = j0 + ct * 16 + lq * 4 + r;
                    p = (j <= irow) ? p : 0.0f;
                }
                lsum += p;
                pk[ct][r] = (short)f2b(p);
            }
        }
#pragma unroll
        for (int dt = 0; dt < 4; ++dt) {
            const int d = dt * 16 + lr;
#pragma unroll
            for (int ct = 0; ct < 4; ++ct) {
                short4v vf = *(const short4v*)
                    &vb[d * 64 + ((((ct << 1) + (lq >> 1)) ^ (lr & 7)) << 3) + ((lq & 1) << 2)];
                of[dt] = mfma_k16(vf, pk[ct], of[dt]);
            }
        }
    };

    stageKV(0, 0);
    for (int jt = 0; jt < ntile; ++jt) {
        const int buf = jt & 1;
        __syncthreads();
        if (jt + 1 < ntile) stageKV(buf ^ 1, jt + 1);
        tile(buf, jt);
    }

    lsum += __shfl_xor(lsum, 16);
    lsum += __shfl_xor(lsum, 32);
    const float inv = fastrcp(lsum);
#pragma unroll
    for (int dt = 0; dt < 4; ++dt)
#pragma unroll
        for (int r = 0; r < 4; ++r)
            Op[(size_t)(dt * 16 + lq * 4 + r) * NN + irow] = f2b(of[dt][r] * inv);
}

// ---------------- combine groups from O^T and transpose: AO[b,n,hh*64+d] = sum_g OT[b,2hh+g][d][n] ----------------
__global__ __launch_bounds__(256) void k_gsum(const u16* __restrict__ OT, u16* __restrict__ AO) {
    __shared__ u16 t[32][34];
    const int b = blockIdx.z;
    const int n0 = blockIdx.x * 32;
    const int c0 = blockIdx.y * 32;
    const int hh = c0 >> 6, d0 = c0 & 63;
    const int tx = threadIdx.x & 31, ty = threadIdx.x >> 5;
    const u16* O0 = OT + ((size_t)(b * QHH + 2 * hh) * 64 + d0) * NN;
    const u16* O1 = OT + ((size_t)(b * QHH + 2 * hh + 1) * 64 + d0) * NN;
#pragma unroll
    for (int i = ty; i < 32; i += 8)
        t[i][tx] = f2b(b2f(O0[(size_t)i * NN + n0 + tx]) + b2f(O1[(size_t)i * NN + n0 + tx]));
    __syncthreads();
#pragma unroll
    for (int i = ty; i < 32; i += 8)
        AO[((size_t)(b * NN) + n0 + i) * 512 + c0 + tx] = t[tx][i];
}

extern "C" void kernel_launch(void* const* d_in, const int* in_sizes, int n_in,
                              void* d_out, int out_size, void* d_ws, size_t ws_size,
                              hipStream_t stream) {
    const float* tokens = (const float*)d_in[0];
    const float* norm_w = (const float*)d_in[1];
    const float* Wq = (const float*)d_in[2];
    const float* Wkv = (const float*)d_in[3];
    const float* Wout = (const float*)d_in[4];
    const float* q_gamma = (const float*)d_in[5];
    const float* k_gamma = (const float*)d_in[6];
    float* out = (float*)d_out;

    char* ws = (char*)d_ws;
    u16* xb = (u16*)(ws + 0);             // 8 MB  [4096,1024]
    u16* WqT = (u16*)(ws + 8388608);      // 2 MB  } adjacent => fused Bt [2048][1024]
    u16* WkvT = (u16*)(ws + 10485760);    // 2 MB  }
    u16* WoutT = (u16*)(ws + 12582912);   // 1 MB
    u16* qkv = (u16*)(ws + 13631488);     // 16 MB fused [4096][2048] (q_raw ∪ kv_raw)
    u16* kn = (u16*)(ws + 30408704);      // 4 MB
    u16* vtb = (u16*)(ws + 34603008);     // 4 MB
    // Lifetime aliases (stream-ordered, no overlap):
    u16* qn = xb;                 // xb dead after fused QKV GEMM
    u16* Obuf = qkv;              // qkv fully consumed by headnorm+vtrans before attn
    u16* AO = (u16*)(ws + 22020096);  // second half of qkv region, dead likewise

    k_rmsnorm<<<4096, 256, 0, stream>>>(tokens, norm_w, xb);
    k_wprep<<<dim3(32, 32, 3), 256, 0, stream>>>(Wq, Wkv, Wout, WqT, WkvT, WoutT);
    // fused QKV GEMM: [4096,1024] x [2048,1024]^T -> [4096,2048]
    k_gemm128<<<dim3(16, 32), 256, 0, stream>>>(xb, WqT, qkv, 4096, 2048, 1024);
    k_headnorm<<<4096, 256, 0, stream>>>(qkv, q_gamma, k_gamma, qn, kn);
    k_vtrans<<<dim3(16, 32), 256, 0, stream>>>(qkv, vtb);
    k_attn<<<dim3(32, 32), 256, 0, stream>>>(qn, kn, vtb, Obuf);
    k_gsum<<<dim3(64, 16, 2), 256, 0, stream>>>(Obuf, AO);
    k_gemm64f<<<dim3(8, 64), 256, 0, stream>>>(AO, WoutT, out, 4096, 1024, 512);
}